// Round 8
// baseline (253.123 us; speedup 1.0000x reference)
//
#include <hip/hip_runtime.h>
#include <hip/hip_bf16.h>
#include <stdint.h>

typedef __hip_bfloat16 bf16;
typedef __attribute__((ext_vector_type(8))) short short8;
typedef __attribute__((ext_vector_type(4))) short short4v;
typedef __attribute__((ext_vector_type(4))) float float4v;

static constexpr int nB = 2, nS = 2048, nD = 1024, nH = 16, nHD = 64;
static constexpr int nBS = nB * nS;   // 4096

#define AS_GLOBAL __attribute__((address_space(1)))
#define AS_LDS    __attribute__((address_space(3)))

union Frag16B { short8 v; uint4 u4; uint2 u2[2]; };

__device__ __forceinline__ void gload_lds16(const void* g, void* l) {
  __builtin_amdgcn_global_load_lds((AS_GLOBAL uint32_t*)(g), (AS_LDS uint32_t*)(l), 16, 0, 0);
}

__device__ __forceinline__ float fast_exp2(float x) {
#if __has_builtin(__builtin_amdgcn_exp2f)
  return __builtin_amdgcn_exp2f(x);
#else
  float r; asm volatile("v_exp_f32 %0, %1" : "=v"(r) : "v"(x)); return r;
#endif
}

// drain LDS ops but NOT vmem: prefetch global loads stay in flight across the barrier
__device__ __forceinline__ void lds_barrier() {
  asm volatile("s_waitcnt lgkmcnt(0)\ns_barrier" ::: "memory");
}

__device__ __forceinline__ void lgkm_wait() {
  asm volatile("s_waitcnt lgkmcnt(0)" ::: "memory");
}

// ---------------------------------------------------------------- prep: cast QKV->bf16, W->W^T bf16, rope tables
__global__ __launch_bounds__(256) void prep_kernel(
    const float* __restrict__ Qin, const float* __restrict__ Kin, const float* __restrict__ Vin,
    const float* __restrict__ Wq, const float* __restrict__ Wk,
    const float* __restrict__ Wv, const float* __restrict__ Wo,
    bf16* __restrict__ Qbf, bf16* __restrict__ Kbf, bf16* __restrict__ Vbf,
    bf16* __restrict__ WqT, bf16* __restrict__ WkT, bf16* __restrict__ WvT, bf16* __restrict__ WoT,
    bf16* __restrict__ cos_t, bf16* __restrict__ sin_t) {
  __shared__ float tile[64][65];
  int bx = blockIdx.x, t = threadIdx.x;
  if (bx < 3072) {
    int tz = bx >> 10, blk = bx & 1023;
    const float* src = tz == 0 ? Qin : tz == 1 ? Kin : Vin;
    bf16* dst = tz == 0 ? Qbf : tz == 1 ? Kbf : Vbf;
#pragma unroll
    for (int i = 0; i < 4; ++i) {
      int idx = blk * 1024 + i * 256 + t;  // float4 index
      float4 v = ((const float4*)src)[idx];
      union { bf16 b[4]; uint2 u; } tmp;
      tmp.b[0] = __float2bfloat16(v.x);
      tmp.b[1] = __float2bfloat16(v.y);
      tmp.b[2] = __float2bfloat16(v.z);
      tmp.b[3] = __float2bfloat16(v.w);
      ((uint2*)dst)[idx] = tmp.u;
    }
  } else if (bx < 4096) {
    int idx = bx - 3072;
    int z = idx >> 8;
    const float* W = z == 0 ? Wq : z == 1 ? Wk : z == 2 ? Wv : Wo;
    bf16* T = z == 0 ? WqT : z == 1 ? WkT : z == 2 ? WvT : WoT;
    int tk = (idx & 15) * 64, tn = ((idx >> 4) & 15) * 64;
    int c = t & 63, r0 = t >> 6;
#pragma unroll
    for (int i = 0; i < 16; ++i) {
      int r = i * 4 + r0;
      tile[r][c] = W[(size_t)(tk + r) * nD + tn + c];
    }
    __syncthreads();
#pragma unroll
    for (int i = 0; i < 16; ++i) {
      int r = i * 4 + r0;
      T[(size_t)(tn + r) * nD + tk + c] = __float2bfloat16(tile[c][r]);
    }
  } else {
    int base = (bx - 4096) * 1024 + t * 4;
#pragma unroll
    for (int i = 0; i < 4; ++i) {
      int e = base + i;
      int s = e >> 5, j = e & 31;
      float inv_freq = powf(100000.0f, -(float)(2 * j) / 64.0f);
      float g = (float)s * inv_freq;
      cos_t[e] = __float2bfloat16(cosf(g));
      sin_t[e] = __float2bfloat16(sinf(g));
    }
  }
}

// ---------------------------------------------------------------- fused projection GEMM, BK=64, xor-swizzled LDS
__global__ __launch_bounds__(256) void gemm_qkv_kernel(
    const bf16* __restrict__ A0, const bf16* __restrict__ A1, const bf16* __restrict__ A2,
    const bf16* __restrict__ Bt0, const bf16* __restrict__ Bt1, const bf16* __restrict__ Bt2,
    bf16* __restrict__ q_h, bf16* __restrict__ k_h, bf16* __restrict__ vt_h,
    const bf16* __restrict__ cos_t, const bf16* __restrict__ sin_t) {
  const int z = blockIdx.z;
  const bf16* A  = z == 0 ? A0 : (z == 1 ? A1 : A2);
  const bf16* Bt = z == 0 ? Bt0 : (z == 1 ? Bt1 : Bt2);

  __shared__ bf16 As[128 * 64];
  __shared__ bf16 Bs[128 * 64];

  const int t = threadIdx.x;
  const int lane = t & 63;
  const int wid = t >> 6;
  const int quad = lane >> 4;
  const int l16 = lane & 15;
  const int wm = wid >> 1;
  const int wn = wid & 1;
  const int m0 = blockIdx.x * 128;   // 32 m-tiles
  const int n0 = blockIdx.y * 128;   // 8 n-tiles
  const int K = nD;
  const int rloc = lane >> 3, cl = lane & 7;
  const int cg = cl ^ rloc;          // xor chunk swizzle

  float4v acc[4][4] = {};

  for (int kt = 0; kt < K; kt += 64) {
    __syncthreads();
#pragma unroll
    for (int p = 0; p < 4; ++p) {
      int rowbase = (p * 4 + wid) * 8;
      gload_lds16(A + (size_t)(m0 + rowbase + rloc) * K + kt + cg * 8, As + (size_t)rowbase * 64);
      gload_lds16(Bt + (size_t)(n0 + rowbase + rloc) * K + kt + cg * 8, Bs + (size_t)rowbase * 64);
    }
    __syncthreads();

#pragma unroll
    for (int ks = 0; ks < 2; ++ks) {
      Frag16B a[4], b[4];
#pragma unroll
      for (int mi = 0; mi < 4; ++mi) {
        int row = wm * 64 + mi * 16 + l16;
        int ch = (ks * 4 + quad) ^ (row & 7);
        a[mi].u4 = *(const uint4*)&As[row * 64 + ch * 8];
      }
#pragma unroll
      for (int ni = 0; ni < 4; ++ni) {
        int row = wn * 64 + ni * 16 + l16;
        int ch = (ks * 4 + quad) ^ (row & 7);
        b[ni].u4 = *(const uint4*)&Bs[row * 64 + ch * 8];
      }
#pragma unroll
      for (int mi = 0; mi < 4; ++mi)
#pragma unroll
        for (int ni = 0; ni < 4; ++ni)
          acc[mi][ni] = __builtin_amdgcn_mfma_f32_16x16x32_bf16(a[mi].v, b[ni].v, acc[mi][ni], 0, 0, 0);
    }
  }

  const int col0 = n0 + wn * 64;   // multiple of 64 -> one head per wave
  if (z <= 1) {
    bf16* dst = z ? k_h : q_h;
#pragma unroll
    for (int mi = 0; mi < 4; ++mi)
#pragma unroll
      for (int r = 0; r < 4; ++r) {
        int row = m0 + wm * 64 + mi * 16 + quad * 4 + r;
        int s = row & (nS - 1);
        float x0 = acc[mi][0][r], x1 = acc[mi][1][r], x2 = acc[mi][2][r], x3 = acc[mi][3][r];
        float y[4];
#pragma unroll
        for (int p = 0; p < 2; ++p) {
          int d = p * 16 + l16;
          float c = __bfloat162float(cos_t[s * 32 + d]);
          float sn = __bfloat162float(sin_t[s * 32 + d]);
          float xa = p ? x1 : x0, xb = p ? x3 : x2;
          y[p] = xa * c + xb * sn;
          y[p + 2] = xb * c - xa * sn;
        }
        float ss = y[0] * y[0] + y[1] * y[1] + y[2] * y[2] + y[3] * y[3];
#pragma unroll
        for (int m = 1; m <= 8; m <<= 1) ss += __shfl_xor(ss, m, 64);
        float inv = 1.0f / sqrtf(ss * (1.0f / 64.0f) + 1e-9f);
#pragma unroll
        for (int ni = 0; ni < 4; ++ni)
          dst[(size_t)row * nD + col0 + ni * 16 + l16] = __float2bfloat16(y[ni] * inv);
      }
  } else {
    // V: write transposed -> vt_h [b][h][d][s]
#pragma unroll
    for (int mi = 0; mi < 4; ++mi)
#pragma unroll
      for (int r = 0; r < 4; ++r) {
        int row = m0 + wm * 64 + mi * 16 + quad * 4 + r;
        int b = row >> 11, s = row & (nS - 1);
#pragma unroll
        for (int ni = 0; ni < 4; ++ni) {
          int col = col0 + ni * 16 + l16;
          int h = col >> 6, d = col & 63;
          vt_h[((size_t)((b * nH + h) * 64 + d)) * nS + s] = __float2bfloat16(acc[mi][ni][r]);
        }
      }
  }
}

// ---------------------------------------------------------------- output GEMM: 64x128 tile, BK=64, grid (64, 8)
__global__ __launch_bounds__(256) void gemm_out_kernel(
    const bf16* __restrict__ A, const bf16* __restrict__ Bt, float* __restrict__ C) {
  __shared__ bf16 As[64 * 64];
  __shared__ bf16 Bs[128 * 64];
  const int t = threadIdx.x;
  const int lane = t & 63;
  const int wid = t >> 6;
  const int quad = lane >> 4;
  const int l16 = lane & 15;
  const int wm = wid >> 1;
  const int wn = wid & 1;
  const int m0 = blockIdx.x * 64;
  const int n0 = blockIdx.y * 128;
  const int K = nD;
  const int rloc = lane >> 3, cl = lane & 7;
  const int cg = cl ^ rloc;

  float4v acc[2][4] = {};
  for (int kt = 0; kt < K; kt += 64) {
    __syncthreads();
#pragma unroll
    for (int p = 0; p < 2; ++p) {
      int rowbase = (p * 4 + wid) * 8;
      gload_lds16(A + (size_t)(m0 + rowbase + rloc) * K + kt + cg * 8, As + (size_t)rowbase * 64);
    }
#pragma unroll
    for (int p = 0; p < 4; ++p) {
      int rowbase = (p * 4 + wid) * 8;
      gload_lds16(Bt + (size_t)(n0 + rowbase + rloc) * K + kt + cg * 8, Bs + (size_t)rowbase * 64);
    }
    __syncthreads();

#pragma unroll
    for (int ks = 0; ks < 2; ++ks) {
      Frag16B a[2], b[4];
#pragma unroll
      for (int mi = 0; mi < 2; ++mi) {
        int row = wm * 32 + mi * 16 + l16;
        int ch = (ks * 4 + quad) ^ (row & 7);
        a[mi].u4 = *(const uint4*)&As[row * 64 + ch * 8];
      }
#pragma unroll
      for (int ni = 0; ni < 4; ++ni) {
        int row = wn * 64 + ni * 16 + l16;
        int ch = (ks * 4 + quad) ^ (row & 7);
        b[ni].u4 = *(const uint4*)&Bs[row * 64 + ch * 8];
      }
#pragma unroll
      for (int mi = 0; mi < 2; ++mi)
#pragma unroll
        for (int ni = 0; ni < 4; ++ni)
          acc[mi][ni] = __builtin_amdgcn_mfma_f32_16x16x32_bf16(a[mi].v, b[ni].v, acc[mi][ni], 0, 0, 0);
    }
  }
#pragma unroll
  for (int mi = 0; mi < 2; ++mi)
#pragma unroll
    for (int ni = 0; ni < 4; ++ni)
#pragma unroll
      for (int r = 0; r < 4; ++r) {
        int row = m0 + wm * 32 + mi * 16 + quad * 4 + r;
        int col = n0 + wn * 64 + ni * 16 + l16;
        C[(size_t)row * nD + col] = acc[mi][ni][r];
      }
}

// ---------------------------------------------------------------- flash attention v7: 128-q x 128-key tiles,
// nkt_max = 16 (wall tracks nkt_max * L_iter), 2 blocks/CU paired long+short same head,
// XCD-pinned bh, double-buffered LDS w/ 4-pass register prefetch across lgkm-only barrier,
// register-resident P, LDS-transpose epilogue.
static constexpr float SC = 0.18033688011112042f;  // 0.125 * log2(e)

__global__ __launch_bounds__(256, 2) void attn_kernel(const bf16* __restrict__ q_h,
                                                      const bf16* __restrict__ k_h,
                                                      const bf16* __restrict__ vt_h,
                                                      bf16* __restrict__ vals) {
  // [ K0(8192) | K1(8192) | V0(8192) | V1(8192) ] bf16 = 64 KB; front 4608 reused as epilogue scratch
  __shared__ bf16 lds_buf[32768];

  const int t = threadIdx.x;
  const int lane = t & 63, wid = t >> 6, quad = lane >> 4, l16 = lane & 15;
  const int id = blockIdx.x;           // 0..511
  const int xcd = id & 7;              // round-robin XCD heuristic (validated r5: FETCH 101->13MB)
  const int j = id >> 3;               // 0..63 per-XCD index
  const int jj = j & 31;
  const int bh = xcd * 4 + (jj & 3);   // 4 heads per XCD; pair blocks share bh
  const int u = jj >> 2;               // 0..7
  const int qt = (j < 32) ? (15 - u) : u;   // long tile first slot, complementary short second
  const int b = bh >> 4, h = bh & 15;

  const bf16* Kbase = k_h + ((size_t)b * nS) * nD + h * 64;
  const bf16* Vbase = vt_h + (size_t)bh * 64 * nS;  // [d][s]

  // K staging: 128 rows x 64 d, 4 passes of 32 rows; row length 8 chunks (16B)
  const int rowK = t >> 3;          // 0..31
  const int clK = t & 7;
  const int cgK = clK ^ (rowK & 7);
  // V staging: 64 rows(d) x 128 keys, 4 passes of 16 rows; row length 16 chunks
  const int rowV = t >> 4;          // 0..15
  const int clV = t & 15;
  const int cgV = clV ^ rowV;       // (row & 15) == rowV per pass
  const int r7 = l16 & 7;

  bf16* const scratch = lds_buf + wid * 1152;  // 16 x 72 per wave per qs round

  const int nkt = qt + 1;                      // 128-key tiles
  const int q0w = qt * 128 + wid * 32;         // wave's first q row

  // Q B-frags (n=q=l16, k=d=quad*8+j), 2 q-slices x 2 d-halves
  Frag16B qf[2][2];
#pragma unroll
  for (int qs = 0; qs < 2; ++qs) {
    const bf16* qp = q_h + ((size_t)(b * nS + q0w + qs * 16 + l16)) * nD + h * 64;
    qf[qs][0].u4 = *(const uint4*)(qp + quad * 8);
    qf[qs][1].u4 = *(const uint4*)(qp + 32 + quad * 8);
  }

  // prologue: load tile 0 into regs (4 passes each)
  uint4 kreg[4], vreg[4];
#pragma unroll
  for (int p = 0; p < 4; ++p) {
    kreg[p] = *(const uint4*)(Kbase + (size_t)(p * 32 + rowK) * nD + cgK * 8);
    vreg[p] = *(const uint4*)(Vbase + (size_t)(p * 16 + rowV) * nS + cgV * 8);
  }

  float4v o_acc[2][4] = {};
  float l_acc[2] = {0.f, 0.f};

  for (int kt = 0; kt < nkt; ++kt) {
    bf16* Kb = lds_buf + (kt & 1) * 8192;
    bf16* Vb = lds_buf + 16384 + (kt & 1) * 8192;
    // staged regs -> LDS (contiguous per wave, conflict-free)
#pragma unroll
    for (int p = 0; p < 4; ++p) {
      *(uint4*)&Kb[(p * 32 + rowK) * 64 + clK * 8] = kreg[p];
      *(uint4*)&Vb[(p * 16 + rowV) * 128 + clV * 8] = vreg[p];
    }
    // prefetch next tile (global loads stay in flight across the barrier)
    if (kt + 1 < nkt) {
#pragma unroll
      for (int p = 0; p < 4; ++p) {
        kreg[p] = *(const uint4*)(Kbase + (size_t)((kt + 1) * 128 + p * 32 + rowK) * nD + cgK * 8);
        vreg[p] = *(const uint4*)(Vbase + (size_t)(p * 16 + rowV) * nS + (kt + 1) * 128 + cgV * 8);
      }
    }
    lds_barrier();

#pragma unroll
    for (int ks = 0; ks < 2; ++ks) {           // two 64-key halves per staged tile
      const int keyb = kt * 128 + ks * 64;     // wave-uniform
      if (keyb > q0w + 31) continue;           // fully masked for this wave

      // S^T[key][q]: A = K frags from LDS
      float4v st[2][4];
#pragma unroll
      for (int kt4 = 0; kt4 < 4; ++kt4) {
        int row = ks * 64 + kt4 * 16 + l16;    // 0..127
        Frag16B k0, k1;
        k0.u4 = *(const uint4*)&Kb[row * 64 + ((quad ^ (row & 7)) * 8)];
        k1.u4 = *(const uint4*)&Kb[row * 64 + (((quad + 4) ^ (row & 7)) * 8)];
#pragma unroll
        for (int qs = 0; qs < 2; ++qs) {
          float4v zz = {};
          zz = __builtin_amdgcn_mfma_f32_16x16x32_bf16(k0.v, qf[qs][0].v, zz, 0, 0, 0);
          st[qs][kt4] = __builtin_amdgcn_mfma_f32_16x16x32_bf16(k1.v, qf[qs][1].v, zz, 0, 0, 0);
        }
      }

      // exp + pack P^T B-frags (k=key=quad*4+r == C-layout row)
      short4v pf[2][4];
      const bool need_mask = (keyb + 63) > q0w;   // wave-uniform
      if (need_mask) {
#pragma unroll
        for (int qs = 0; qs < 2; ++qs) {
          int qg = q0w + qs * 16 + l16;
#pragma unroll
          for (int kt4 = 0; kt4 < 4; ++kt4) {
            int key0 = keyb + kt4 * 16 + quad * 4;
#pragma unroll
            for (int r = 0; r < 4; ++r) {
              float x = st[qs][kt4][r] * SC;
              if (key0 + r > qg) x = -12000.0f;
              float p = fast_exp2(x);
              l_acc[qs] += p;
              union { bf16 hh; short ss; } cv;
              cv.hh = __float2bfloat16(p);
              pf[qs][kt4][r] = cv.ss;
            }
          }
        }
      } else {
#pragma unroll
        for (int qs = 0; qs < 2; ++qs)
#pragma unroll
          for (int kt4 = 0; kt4 < 4; ++kt4)
#pragma unroll
            for (int r = 0; r < 4; ++r) {
              float p = fast_exp2(st[qs][kt4][r] * SC);
              l_acc[qs] += p;
              union { bf16 hh; short ss; } cv;
              cv.hh = __float2bfloat16(p);
              pf[qs][kt4][r] = cv.ss;
            }
      }

      // O^T[d][q] += V^T·P^T ; V frags shared across q-slices
#pragma unroll
      for (int dt = 0; dt < 4; ++dt) {
        int row = dt * 16 + l16;
#pragma unroll
        for (int kt4 = 0; kt4 < 4; ++kt4) {
          int chunk = ks * 8 + kt4 * 2 + (quad >> 1);
          union { uint2 u; short4v s; } vv;
          vv.u = *(const uint2*)&Vb[row * 128 + ((chunk ^ l16) * 8) + (quad & 1) * 4];
          o_acc[0][dt] = __builtin_amdgcn_mfma_f32_16x16x16bf16_1k(vv.s, pf[0][kt4], o_acc[0][dt], 0, 0, 0);
          o_acc[1][dt] = __builtin_amdgcn_mfma_f32_16x16x16bf16_1k(vv.s, pf[1][kt4], o_acc[1][dt], 0, 0, 0);
        }
      }
    }
  }

  // ---- epilogue: row-sum reduce, LDS-transpose, coalesced 16B stores
  lds_barrier();  // all waves done reading K/V before scratch overwrites them
#pragma unroll
  for (int qs = 0; qs < 2; ++qs) {
    float la = l_acc[qs];
    la += __shfl_xor(la, 16, 64);
    la += __shfl_xor(la, 32, 64);
    float inv_l = 1.0f / la;
    // write transposed: scratch[q_loc=l16][d]
#pragma unroll
    for (int dt = 0; dt < 4; ++dt) {
      union { bf16 b2[2]; uint u; } p01, p23;
      p01.b2[0] = __float2bfloat16(o_acc[qs][dt][0] * inv_l);
      p01.b2[1] = __float2bfloat16(o_acc[qs][dt][1] * inv_l);
      p23.b2[0] = __float2bfloat16(o_acc[qs][dt][2] * inv_l);
      p23.b2[1] = __float2bfloat16(o_acc[qs][dt][3] * inv_l);
      *(uint*)&scratch[l16 * 72 + dt * 16 + quad * 4] = p01.u;
      *(uint*)&scratch[l16 * 72 + dt * 16 + quad * 4 + 2] = p23.u;
    }
    lgkm_wait();  // own writes visible to own reads
    uint4 r0 = *(const uint4*)&scratch[l16 * 72 + quad * 16];
    uint4 r1 = *(const uint4*)&scratch[l16 * 72 + quad * 16 + 8];
    int qrow = q0w + qs * 16 + l16;
    bf16* vp = vals + ((size_t)(b * nS + qrow)) * nD + h * 64 + quad * 16;
    *(uint4*)(vp) = r0;
    *(uint4*)(vp + 8) = r1;
    lgkm_wait();  // reads done before next qs overwrites region
  }
}

// ---------------------------------------------------------------- launch
extern "C" void kernel_launch(void* const* d_in, const int* in_sizes, int n_in,
                              void* d_out, int out_size, void* d_ws, size_t ws_size,
                              hipStream_t stream) {
  const float* Qin = (const float*)d_in[0];
  const float* Kin = (const float*)d_in[1];
  const float* Vin = (const float*)d_in[2];
  const float* Wq = (const float*)d_in[4];
  const float* Wk = (const float*)d_in[5];
  const float* Wv = (const float*)d_in[6];
  const float* Wo = (const float*)d_in[7];
  float* out = (float*)d_out;

  char* ws = (char*)d_ws;
  const size_t MB = 1u << 20;
  bf16* Qbf = (bf16*)(ws + 0 * MB);
  bf16* Kbf = (bf16*)(ws + 8 * MB);
  bf16* Vbf = (bf16*)(ws + 16 * MB);
  bf16* WqT = (bf16*)(ws + 24 * MB);
  bf16* WkT = (bf16*)(ws + 26 * MB);
  bf16* WvT = (bf16*)(ws + 28 * MB);
  bf16* WoT = (bf16*)(ws + 30 * MB);
  bf16* cos_t = (bf16*)(ws + 32 * MB);
  bf16* sin_t = (bf16*)(ws + 33 * MB);
  bf16* q_h = (bf16*)(ws + 34 * MB);
  bf16* k_h = (bf16*)(ws + 42 * MB);
  bf16* vt_h = (bf16*)(ws + 50 * MB);
  bf16* vals = (bf16*)(ws + 58 * MB);

  prep_kernel<<<4160, 256, 0, stream>>>(Qin, Kin, Vin, Wq, Wk, Wv, Wo,
                                        Qbf, Kbf, Vbf, WqT, WkT, WvT, WoT, cos_t, sin_t);

  gemm_qkv_kernel<<<dim3(32, 8, 3), 256, 0, stream>>>(Qbf, Kbf, Vbf, WqT, WkT, WvT,
                                                      q_h, k_h, vt_h, cos_t, sin_t);

  attn_kernel<<<512, 256, 0, stream>>>(q_h, k_h, vt_h, vals);

  gemm_out_kernel<<<dim3(64, 8), 256, 0, stream>>>(vals, WoT, out);
}